// Round 11
// baseline (130.588 us; speedup 1.0000x reference)
//
#include <hip/hip_runtime.h>
#include <hip/hip_bf16.h>
#include <cstdint>
#include <cstddef>

#define NS 2560
#define NQ 8192
#define NC 512
#define DD 1600

typedef __bf16 bf16_t;
typedef __bf16 bf16x8 __attribute__((ext_vector_type(8)));
typedef float f32x4 __attribute__((ext_vector_type(4)));

// ---------------------------------------------------------------------------
// Kernel 1: class-mean prototypes (bf16) + ||p||^2 (fp32). One block per class.
// ---------------------------------------------------------------------------
__global__ __launch_bounds__(256) void proto_kernel(
    const float* __restrict__ sup, const int* __restrict__ lab,
    bf16_t* __restrict__ protos, float* __restrict__ p2)
{
    const int m   = blockIdx.x;
    const int tid = threadIdx.x;
    __shared__ int   idxs[32];
    __shared__ int   cnt;
    __shared__ float wsum[4];
    if (tid == 0) cnt = 0;
    __syncthreads();
    for (int i = tid; i < NS; i += 256) {
        if (lab[i] == m) {
            int p = atomicAdd(&cnt, 1);
            if (p < 32) idxs[p] = i;
        }
    }
    __syncthreads();
    int n = cnt < 32 ? cnt : 32;
    if (tid == 0 && n > 1) {                       // deterministic order
        for (int a = 1; a < n; ++a) {
            int key = idxs[a]; int b = a - 1;
            while (b >= 0 && idxs[b] > key) { idxs[b+1] = idxs[b]; --b; }
            idxs[b+1] = key;
        }
    }
    __syncthreads();

    float acc[7];
    #pragma unroll
    for (int u = 0; u < 7; ++u) acc[u] = 0.f;
    for (int t = 0; t < n; ++t) {
        const float* src = sup + (size_t)idxs[t] * DD;
        #pragma unroll
        for (int u = 0; u < 7; ++u) {
            int j = tid + u * 256;
            if (j < DD) acc[u] += src[j];
        }
    }
    float inv = (n > 0) ? 1.f / (float)n : 0.f;
    float psq = 0.f;
    #pragma unroll
    for (int u = 0; u < 7; ++u) {
        int j = tid + u * 256;
        if (j < DD) {
            float p = acc[u] * inv;
            bf16_t pb = (bf16_t)p;
            protos[(size_t)m * DD + j] = pb;
            float pf = (float)pb;
            psq += pf * pf;
        }
    }
    #pragma unroll
    for (int o = 32; o > 0; o >>= 1) psq += __shfl_xor(psq, o);
    int lane = tid & 63, wid = tid >> 6;
    if (lane == 0) wsum[wid] = psq;
    __syncthreads();
    if (tid == 0) p2[m] = wsum[0] + wsum[1] + wsum[2] + wsum[3];
}

// ---------------------------------------------------------------------------
// Fused GEMM + log_softmax, 3-stage software pipeline (T3/T4):
//   BM=32 rows x BN=512 cols (all classes) per block, BK=32, 50 iters,
//   8 waves (wave = 64-col strip), grid 256.
//   B: k-major LDS tiles [gsec(4)][col(512)][16B] = 32 KB, TRIPLE buffered,
//      staged 2 tiles ahead via global_load_lds; linear dest == k-major
//      layout, b128 reads are conflict-free with no swizzle.
//   A: NEVER in LDS. Per-lane frag = 8 contiguous fp32 -> 2 float4 direct
//      loads, 3 named reg slots, 2 tiles ahead, fp32->bf16 cvt at use.
//   Sync: counted s_waitcnt vmcnt(12) (steady queue: A(t),B(t),A(t+1),
//      B(t+1),A(t+2) -> drain oldest 8, B(t) guaranteed) + RAW s_barrier.
//   No ds_write anywhere; no vmcnt(0) until the last two iterations.
// ---------------------------------------------------------------------------
struct ASlot { float4 f[4]; };   // [mi][half], static indices only

__device__ __forceinline__ void issueA(ASlot& s, const float* a0,
                                       const float* a1, int t)
{
    const float* p0 = a0 + t * 32;
    const float* p1 = a1 + t * 32;
    s.f[0] = *(const float4*)(p0);
    s.f[1] = *(const float4*)(p0 + 4);
    s.f[2] = *(const float4*)(p1);
    s.f[3] = *(const float4*)(p1 + 4);
}

__device__ __forceinline__ void issueB(const bf16_t* __restrict__ protos,
                                       char* buf, int k0, int tid, int wid)
{
    #pragma unroll
    for (int p = 0; p < 4; ++p) {
        int idx = p * 512 + tid;          // 16B granule: (gsec, col)
        int c   = idx & 511;
        int gs  = idx >> 9;
        const bf16_t* src = protos + (size_t)c * DD + k0 + gs * 8;
        char* dst = buf + (size_t)(p * 512 + wid * 64) * 16;  // wave-uniform
        __builtin_amdgcn_global_load_lds(
            (const __attribute__((address_space(1))) void*)src,
            (__attribute__((address_space(3))) void*)dst, 16, 0, 0);
    }
}

template<int VM>
__device__ __forceinline__ void kwait()
{
    if constexpr (VM == 12)     asm volatile("s_waitcnt vmcnt(12)" ::: "memory");
    else if constexpr (VM == 8) asm volatile("s_waitcnt vmcnt(8)"  ::: "memory");
    else                        asm volatile("s_waitcnt vmcnt(0)"  ::: "memory");
}

__device__ __forceinline__ void computeT(const char* buf, const ASlot& s,
                                         f32x4 (&acc)[2][4], int rdoff)
{
    bf16x8 af[2];
    #pragma unroll
    for (int mi = 0; mi < 2; ++mi) {
        float4 lo = s.f[2 * mi], hi = s.f[2 * mi + 1];
        bf16x8 w;
        w[0] = (bf16_t)lo.x; w[1] = (bf16_t)lo.y;
        w[2] = (bf16_t)lo.z; w[3] = (bf16_t)lo.w;
        w[4] = (bf16_t)hi.x; w[5] = (bf16_t)hi.y;
        w[6] = (bf16_t)hi.z; w[7] = (bf16_t)hi.w;
        af[mi] = w;
    }
    bf16x8 bfr[4];
    #pragma unroll
    for (int ni = 0; ni < 4; ++ni)
        bfr[ni] = *(const bf16x8*)(buf + rdoff + ni * 256);
    #pragma unroll
    for (int mi = 0; mi < 2; ++mi)
        #pragma unroll
        for (int ni = 0; ni < 4; ++ni)
            acc[mi][ni] = __builtin_amdgcn_mfma_f32_16x16x32_bf16(
                af[mi], bfr[ni], acc[mi][ni], 0, 0, 0);
}

__global__ __launch_bounds__(512, 1) void fused_kernel(
    const float* __restrict__ q, const bf16_t* __restrict__ protos,
    const float* __restrict__ p2, float* __restrict__ out)
{
    extern __shared__ char smem[];    // 3 x 32 KB B buffers

    const int tid  = threadIdx.x;
    const int lane = tid & 63;
    const int wid  = tid >> 6;        // wave = 64-col strip 0..7
    const int r    = lane & 15;
    const int g    = lane >> 4;       // k-octet 0..3 (BK=32)
    const int m0   = blockIdx.x * 32;

    const float* ab0 = q + (size_t)(m0 + r) * DD + g * 8;
    const float* ab1 = ab0 + (size_t)16 * DD;
    const int rdoff  = g * 8192 + (wid * 64 + r) * 16;

    f32x4 acc[2][4];
    #pragma unroll
    for (int mi = 0; mi < 2; ++mi)
        #pragma unroll
        for (int ni = 0; ni < 4; ++ni)
            acc[mi][ni] = (f32x4){0.f, 0.f, 0.f, 0.f};

    ASlot s0, s1, s2;

    // ---- prologue: tiles 0 and 1 (A-issue then B-issue, steady-state order) ----
    issueA(s0, ab0, ab1, 0);
    issueB(protos, smem,          0, tid, wid);
    issueA(s1, ab0, ab1, 1);
    issueB(protos, smem + 32768, 32, tid, wid);

#define GITER(T, SL, SU, BL, BU, VM, DOPRE)                                   \
    {                                                                         \
        if (DOPRE) issueA(SL, ab0, ab1, (T) + 2);                             \
        kwait<VM>();                                                          \
        asm volatile("s_barrier" ::: "memory");                               \
        if (DOPRE) issueB(protos, smem + (size_t)(BL) * 32768,                \
                          ((T) + 2) * 32, tid, wid);                          \
        computeT(smem + (size_t)(BU) * 32768, SU, acc, rdoff);                \
    }

    for (int tt = 0; tt < 48; tt += 3) {
        GITER(tt,     s2, s0, 2, 0, 12, true);
        GITER(tt + 1, s0, s1, 0, 1, 12, true);
        GITER(tt + 2, s1, s2, 1, 2, 12, true);
    }
    GITER(48, s2, s0, 2, 0, 8, false);
    GITER(49, s0, s1, 0, 1, 0, false);
#undef GITER

    __syncthreads();   // loop done; reuse smem for softmax reduction

    // ---- logits = 2*dot - |p|^2 ----
    float p2c[4];
    #pragma unroll
    for (int ni = 0; ni < 4; ++ni) p2c[ni] = p2[wid * 64 + ni * 16 + r];
    #pragma unroll
    for (int mi = 0; mi < 2; ++mi)
        #pragma unroll
        for (int ni = 0; ni < 4; ++ni)
            #pragma unroll
            for (int j = 0; j < 4; ++j)
                acc[mi][ni][j] = 2.f * acc[mi][ni][j] - p2c[ni];

    // ---- fused log_softmax over 512 cols ----
    float* red  = (float*)smem;   // [32][8]
    float* gmax = red + 256;      // [32]
    float* lse  = gmax + 32;      // [32]

    float rmax[2][4];
    #pragma unroll
    for (int mi = 0; mi < 2; ++mi)
        #pragma unroll
        for (int j = 0; j < 4; ++j) {
            float m = acc[mi][0][j];
            #pragma unroll
            for (int ni = 1; ni < 4; ++ni) m = fmaxf(m, acc[mi][ni][j]);
            rmax[mi][j] = m;
        }
    #pragma unroll
    for (int o = 1; o < 16; o <<= 1)
        #pragma unroll
        for (int mi = 0; mi < 2; ++mi)
            #pragma unroll
            for (int j = 0; j < 4; ++j)
                rmax[mi][j] = fmaxf(rmax[mi][j], __shfl_xor(rmax[mi][j], o));
    if (r == 0) {
        #pragma unroll
        for (int mi = 0; mi < 2; ++mi)
            #pragma unroll
            for (int j = 0; j < 4; ++j)
                red[(mi * 16 + g * 4 + j) * 8 + wid] = rmax[mi][j];
    }
    __syncthreads();
    if (tid < 32) {
        float m = red[tid * 8];
        #pragma unroll
        for (int w = 1; w < 8; ++w) m = fmaxf(m, red[tid * 8 + w]);
        gmax[tid] = m;
    }
    __syncthreads();

    float rsum[2][4];
    #pragma unroll
    for (int mi = 0; mi < 2; ++mi)
        #pragma unroll
        for (int j = 0; j < 4; ++j) {
            float gm = gmax[mi * 16 + g * 4 + j];
            float s = 0.f;
            #pragma unroll
            for (int ni = 0; ni < 4; ++ni) s += expf(acc[mi][ni][j] - gm);
            rsum[mi][j] = s;
        }
    #pragma unroll
    for (int o = 1; o < 16; o <<= 1)
        #pragma unroll
        for (int mi = 0; mi < 2; ++mi)
            #pragma unroll
            for (int j = 0; j < 4; ++j)
                rsum[mi][j] += __shfl_xor(rsum[mi][j], o);
    if (r == 0) {
        #pragma unroll
        for (int mi = 0; mi < 2; ++mi)
            #pragma unroll
            for (int j = 0; j < 4; ++j)
                red[(mi * 16 + g * 4 + j) * 8 + wid] = rsum[mi][j];
    }
    __syncthreads();
    if (tid < 32) {
        float s = 0.f;
        #pragma unroll
        for (int w = 0; w < 8; ++w) s += red[tid * 8 + w];
        lse[tid] = gmax[tid] + logf(s);
    }
    __syncthreads();

    // ---- write output ----
    #pragma unroll
    for (int mi = 0; mi < 2; ++mi) {
        #pragma unroll
        for (int j = 0; j < 4; ++j) {
            float l = lse[mi * 16 + g * 4 + j];
            size_t rowoff = (size_t)(m0 + mi * 16 + g * 4 + j) * NC;
            #pragma unroll
            for (int ni = 0; ni < 4; ++ni)
                out[rowoff + wid * 64 + ni * 16 + r] = acc[mi][ni][j] - l;
        }
    }
}

// ---------------------------------------------------------------------------
extern "C" void kernel_launch(void* const* d_in, const int* in_sizes, int n_in,
                              void* d_out, int out_size, void* d_ws, size_t ws_size,
                              hipStream_t stream)
{
    const float* sup = (const float*)d_in[0];   // [2560,64,5,5]
    const float* qry = (const float*)d_in[1];   // [8192,64,5,5]
    const int*   lab = (const int*)d_in[2];     // [2560]
    float* out = (float*)d_out;                 // [8192,512]

    char* ws = (char*)d_ws;
    bf16_t* protos = (bf16_t*)ws;               // 512*1600*2 = 1,638,400 B
    float*  p2     = (float*)(ws + 1638400);    // 2 KB

    const int smem_bytes = 98304;               // 3 x 32 KB B buffers
    hipFuncSetAttribute(reinterpret_cast<const void*>(fused_kernel),
                        hipFuncAttributeMaxDynamicSharedMemorySize, smem_bytes);

    proto_kernel<<<NC, 256, 0, stream>>>(sup, lab, protos, p2);
    fused_kernel<<<NQ / 32, 512, smem_bytes, stream>>>(qry, protos, p2, out);
}